// Round 2
// baseline (584.038 us; speedup 1.0000x reference)
//
#include <hip/hip_runtime.h>
#include <hip/hip_bf16.h>
#include <cstdint>

// Problem: out[M,N] = A[M,K] (fp32) x W[N,K] (int8, stored as int32 per harness) * scale[N]
// M=8192 N=4096 K=4096
#define M_DIM 8192
#define N_DIM 4096
#define K_DIM 4096

typedef unsigned short u16;
typedef unsigned int u32;
typedef __attribute__((ext_vector_type(8))) short short8;     // 8 x bf16 (4 VGPRs)
typedef __attribute__((ext_vector_type(4))) float floatx4;    // MFMA accumulator

#define AS1 __attribute__((address_space(1)))
#define AS3 __attribute__((address_space(3)))

static __device__ __forceinline__ u16 f2bf(float f) {
    // round-to-nearest-even fp32 -> bf16 (inputs are finite normals)
    u32 x = __float_as_uint(f);
    x += 0x7FFFu + ((x >> 16) & 1u);
    return (u16)(x >> 16);
}

// ---------------- detect: is W stored as int32 (one per element) or packed int8? ----------------
// int32 storage: every word in [-127,126]. Packed int8: 4 random bytes/word -> |v|>130 almost surely.
__global__ void detect_kernel(const int* __restrict__ w, int* __restrict__ flag) {
    if (threadIdx.x == 0 && blockIdx.x == 0) {
        int bad = 0;
        for (int i = 0; i < 256; ++i) {
            int v = w[i];
            if (v > 130 || v < -130) bad = 1;
        }
        *flag = bad;  // 1 = packed int8, 0 = int32 elements
    }
}

// ---------------- prepass: A fp32 -> bf16 ----------------
__global__ void cvt_a_kernel(const float4* __restrict__ in, ushort4* __restrict__ out, int n4) {
    int i = blockIdx.x * blockDim.x + threadIdx.x;
    int stride = gridDim.x * blockDim.x;
    for (; i < n4; i += stride) {
        float4 f = in[i];
        ushort4 u;
        u.x = f2bf(f.x); u.y = f2bf(f.y); u.z = f2bf(f.z); u.w = f2bf(f.w);
        out[i] = u;
    }
}

// ---------------- prepass: W (int32 elements OR packed int8) -> bf16 ----------------
__global__ void cvt_w_kernel(const int* __restrict__ in, ushort4* __restrict__ out, int n4,
                             const int* __restrict__ flag) {
    const bool packed = (*flag != 0);
    int i = blockIdx.x * blockDim.x + threadIdx.x;
    int stride = gridDim.x * blockDim.x;
    if (!packed) {
        const int4* in4 = (const int4*)in;   // 4 int32 -> 4 bf16
        for (; i < n4; i += stride) {
            int4 w = in4[i];
            ushort4 u;
            u.x = f2bf((float)w.x);
            u.y = f2bf((float)w.y);
            u.z = f2bf((float)w.z);
            u.w = f2bf((float)w.w);
            out[i] = u;
        }
    } else {
        for (; i < n4; i += stride) {        // 1 int32 = 4 packed int8 -> 4 bf16
            int w = in[i];
            ushort4 u;
            u.x = f2bf((float)(signed char)(w        & 0xff));
            u.y = f2bf((float)(signed char)((w >> 8)  & 0xff));
            u.z = f2bf((float)(signed char)((w >> 16) & 0xff));
            u.w = f2bf((float)(signed char)((w >> 24) & 0xff));
            out[i] = u;
        }
    }
}

// ---------------- main GEMM: m97 structure ----------------
// 128x128 tile, BK=32, 256 threads = 4 waves in 2x2, each wave 4x4 of 16x16x32 bf16 MFMA.
// A (bf16 [M,K]) and W (bf16 [N,K], i.e. B^T) staged to LDS via global_load_lds width=16.
__global__ void __launch_bounds__(256)
gemm_bf16_kernel(const u16* __restrict__ A, const u16* __restrict__ W,
                 const float* __restrict__ scaler, float* __restrict__ out) {
    __shared__ u16 As[128 * 32];   // 8 KB, row-major [row][k], row stride 64 B
    __shared__ u16 Bs[128 * 32];   // 8 KB

    const int tid  = threadIdx.x;
    const int wave = tid >> 6;
    const int lane = tid & 63;
    const int r = lane & 15;       // MFMA row/col within 16
    const int q = lane >> 4;       // quad 0..3

    const int mBase = blockIdx.y * 128;
    const int nBase = blockIdx.x * 128;
    const int waveM = wave >> 1;   // 0..1
    const int waveN = wave & 1;    // 0..1

    floatx4 acc[4][4] = {};

    // staging: within a wave, lane l covers tile row (l>>2), 16B chunk (l&3);
    // wave w covers rows w*16..w*16+15 (dst = base + w*1024, HW adds lane*16)
    const int rowA  = tid >> 2;    // 0..63 across block
    const int chunk = tid & 3;
    const u16* aSrc0 = A + (size_t)(mBase + rowA) * K_DIM + chunk * 8;
    const u16* aSrc1 = A + (size_t)(mBase + 64 + rowA) * K_DIM + chunk * 8;
    const u16* bSrc0 = W + (size_t)(nBase + rowA) * K_DIM + chunk * 8;
    const u16* bSrc1 = W + (size_t)(nBase + 64 + rowA) * K_DIM + chunk * 8;
    char* aDst0 = (char*)As + wave * 1024;
    char* aDst1 = (char*)As + 4096 + wave * 1024;
    char* bDst0 = (char*)Bs + wave * 1024;
    char* bDst1 = (char*)Bs + 4096 + wave * 1024;

    // fragment read bases: lane reads [outer=r][k = q*8 .. q*8+7]
    const u16* aRead = As + (waveM * 64 + r) * 32 + q * 8;
    const u16* bRead = Bs + (waveN * 64 + r) * 32 + q * 8;

    for (int kt = 0; kt < K_DIM / 32; ++kt) {
        const int kOff = kt * 32;
        __builtin_amdgcn_global_load_lds((const AS1 u32*)(const void*)(aSrc0 + kOff),
                                         (AS3 u32*)(void*)aDst0, 16, 0, 0);
        __builtin_amdgcn_global_load_lds((const AS1 u32*)(const void*)(aSrc1 + kOff),
                                         (AS3 u32*)(void*)aDst1, 16, 0, 0);
        __builtin_amdgcn_global_load_lds((const AS1 u32*)(const void*)(bSrc0 + kOff),
                                         (AS3 u32*)(void*)bDst0, 16, 0, 0);
        __builtin_amdgcn_global_load_lds((const AS1 u32*)(const void*)(bSrc1 + kOff),
                                         (AS3 u32*)(void*)bDst1, 16, 0, 0);
        __syncthreads();  // compiler emits vmcnt(0) drain before s_barrier

        short8 a[4], b[4];
#pragma unroll
        for (int mt = 0; mt < 4; ++mt) a[mt] = *(const short8*)(aRead + mt * 16 * 32);
#pragma unroll
        for (int nt = 0; nt < 4; ++nt) b[nt] = *(const short8*)(bRead + nt * 16 * 32);
#pragma unroll
        for (int mt = 0; mt < 4; ++mt)
#pragma unroll
            for (int nt = 0; nt < 4; ++nt)
                acc[mt][nt] = __builtin_amdgcn_mfma_f32_16x16x32_bf16(a[mt], b[nt], acc[mt][nt], 0, 0, 0);

        __syncthreads();  // protect LDS before next stage overwrites
    }

    // epilogue: C/D layout col(n)=lane&15, row(m)=q*4+reg; fuse per-channel scale
    const int mW = mBase + waveM * 64;
    const int nW = nBase + waveN * 64;
#pragma unroll
    for (int nt = 0; nt < 4; ++nt) {
        const int n = nW + nt * 16 + r;
        const float s = scaler[n];
#pragma unroll
        for (int mt = 0; mt < 4; ++mt) {
            const int m0 = mW + mt * 16 + q * 4;
#pragma unroll
            for (int j = 0; j < 4; ++j)
                out[(size_t)(m0 + j) * N_DIM + n] = acc[mt][nt][j] * s;
        }
    }
}

// ---------------- fallback (ws too small): fp32 vector GEMM, W as int32 ----------------
__global__ void __launch_bounds__(256)
gemm_fallback_kernel(const float* __restrict__ A, const int* __restrict__ W,
                     const float* __restrict__ scaler, float* __restrict__ out) {
    __shared__ float As[64][33];
    __shared__ float Ws[64][33];
    const int tx = threadIdx.x & 15, ty = threadIdx.x >> 4;
    const int mBase = blockIdx.y * 64, nBase = blockIdx.x * 64;
    float acc[4][4] = {};
    for (int kt = 0; kt < K_DIM; kt += 32) {
        for (int i = threadIdx.x; i < 64 * 32; i += 256) {
            int rr = i >> 5, cc = i & 31;
            As[rr][cc] = A[(size_t)(mBase + rr) * K_DIM + kt + cc];
            Ws[rr][cc] = (float)W[(size_t)(nBase + rr) * K_DIM + kt + cc];
        }
        __syncthreads();
        for (int kk = 0; kk < 32; ++kk) {
            float av[4], bv[4];
#pragma unroll
            for (int i = 0; i < 4; ++i) av[i] = As[ty * 4 + i][kk];
#pragma unroll
            for (int j = 0; j < 4; ++j) bv[j] = Ws[tx * 4 + j][kk];
#pragma unroll
            for (int i = 0; i < 4; ++i)
#pragma unroll
                for (int j = 0; j < 4; ++j) acc[i][j] += av[i] * bv[j];
        }
        __syncthreads();
    }
#pragma unroll
    for (int i = 0; i < 4; ++i)
#pragma unroll
        for (int j = 0; j < 4; ++j) {
            int m = mBase + ty * 4 + i, n = nBase + tx * 4 + j;
            out[(size_t)m * N_DIM + n] = acc[i][j] * scaler[n];
        }
}

extern "C" void kernel_launch(void* const* d_in, const int* in_sizes, int n_in,
                              void* d_out, int out_size, void* d_ws, size_t ws_size,
                              hipStream_t stream) {
    const float* A      = (const float*)d_in[0];
    const int*   W32    = (const int*)d_in[1];   // harness materializes integer inputs as int32
    const float* scaler = (const float*)d_in[2];
    float* out          = (float*)d_out;

    const size_t needA = (size_t)M_DIM * K_DIM * sizeof(u16);  // 64 MiB
    const size_t needW = (size_t)N_DIM * K_DIM * sizeof(u16);  // 32 MiB

    if (ws_size >= needA + needW + 64) {
        u16* Abf  = (u16*)d_ws;
        u16* Wbf  = (u16*)((char*)d_ws + needA);
        int* flag = (int*)((char*)d_ws + needA + needW);
        detect_kernel<<<1, 64, 0, stream>>>(W32, flag);
        cvt_a_kernel<<<4096, 256, 0, stream>>>((const float4*)A, (ushort4*)Abf, M_DIM * K_DIM / 4);
        cvt_w_kernel<<<2048, 256, 0, stream>>>(W32, (ushort4*)Wbf, N_DIM * K_DIM / 4, flag);
        dim3 grid(N_DIM / 128, M_DIM / 128);  // x = N tiles so consecutive blocks share the A slice
        gemm_bf16_kernel<<<grid, 256, 0, stream>>>(Abf, Wbf, scaler, out);
    } else {
        dim3 grid(N_DIM / 64, M_DIM / 64);
        gemm_fallback_kernel<<<grid, 256, 0, stream>>>(A, W32, scaler, out);
    }
}

// Round 3
// 570.046 us; speedup vs baseline: 1.0245x; 1.0245x over previous
//
#include <hip/hip_runtime.h>
#include <hip/hip_bf16.h>
#include <cstdint>

// out[M,N] = A[M,K] (fp32) x W[N,K] (int8 stored as int32 by harness — verified R1/R2) * scale[N]
// M=8192 N=4096 K=4096
#define M_DIM 8192
#define N_DIM 4096
#define K_DIM 4096

typedef unsigned short u16;
typedef unsigned int u32;
typedef __attribute__((ext_vector_type(8))) short short8;     // 8 x bf16 (4 VGPRs)
typedef __attribute__((ext_vector_type(4))) float floatx4;    // MFMA accumulator

#define AS1 __attribute__((address_space(1)))
#define AS3 __attribute__((address_space(3)))

static __device__ __forceinline__ u16 f2bf(float f) {
    // round-to-nearest-even fp32 -> bf16 (inputs are finite normals)
    u32 x = __float_as_uint(f);
    x += 0x7FFFu + ((x >> 16) & 1u);
    return (u16)(x >> 16);
}

// ---------------- prepass: A fp32 -> bf16 ----------------
__global__ void cvt_a_kernel(const float4* __restrict__ in, ushort4* __restrict__ out, int n4) {
    int i = blockIdx.x * blockDim.x + threadIdx.x;
    int stride = gridDim.x * blockDim.x;
    for (; i < n4; i += stride) {
        float4 f = in[i];
        ushort4 u;
        u.x = f2bf(f.x); u.y = f2bf(f.y); u.z = f2bf(f.z); u.w = f2bf(f.w);
        out[i] = u;
    }
}

// ---------------- prepass: W int32 elements -> bf16 (int8 values are exact in bf16) ------------
__global__ void cvt_w_kernel(const int4* __restrict__ in, ushort4* __restrict__ out, int n4) {
    int i = blockIdx.x * blockDim.x + threadIdx.x;
    int stride = gridDim.x * blockDim.x;
    for (; i < n4; i += stride) {
        int4 w = in[i];
        ushort4 u;
        u.x = f2bf((float)w.x);
        u.y = f2bf((float)w.y);
        u.z = f2bf((float)w.z);
        u.w = f2bf((float)w.w);
        out[i] = u;
    }
}

// ---------------- main GEMM: m97 structure + XOR bank-conflict swizzle ----------------
// 128x128 tile, BK=32, 256 threads = 4 waves in 2x2, each wave 4x4 of 16x16x32 bf16 MFMA.
// LDS layout: [row][chunk] with 16B chunks; chunk position p of row r holds global chunk
// p ^ ((r>>1)&3). Writer permutes per-lane SOURCE addresses (same 64B line -> coalescing
// unchanged; global_load_lds dst stays lane-contiguous). Reader folds the swizzle into the
// read base: q -> q ^ ((r>>1)&3). Bank groups become 4*(r&1) + (q^swz): exact 2-way (free).
__global__ void __launch_bounds__(256)
gemm_bf16_kernel(const u16* __restrict__ A, const u16* __restrict__ W,
                 const float* __restrict__ scaler, float* __restrict__ out) {
    __shared__ u16 As[128 * 32];   // 8 KB, row stride 64 B
    __shared__ u16 Bs[128 * 32];   // 8 KB

    const int tid  = threadIdx.x;
    const int wave = tid >> 6;
    const int lane = tid & 63;
    const int r = lane & 15;       // MFMA row/col within 16
    const int q = lane >> 4;       // quad 0..3

    const int mBase = blockIdx.y * 128;
    const int nBase = blockIdx.x * 128;
    const int waveM = wave >> 1;   // 0..1
    const int waveN = wave & 1;    // 0..1

    floatx4 acc[4][4] = {};

    // staging: lane covers tile row (tid>>2), 16B chunk position (tid&3); source chunk is
    // XOR-swizzled. swz is identical for row and row+64 (64>>1 = 32 ≡ 0 mod 4).
    const int rowA  = tid >> 2;                  // 0..63
    const int swzW  = (rowA >> 1) & 3;
    const int chunk = (tid & 3) ^ swzW;          // global chunk to fetch
    const u16* aSrc0 = A + (size_t)(mBase + rowA) * K_DIM + chunk * 8;
    const u16* aSrc1 = A + (size_t)(mBase + 64 + rowA) * K_DIM + chunk * 8;
    const u16* bSrc0 = W + (size_t)(nBase + rowA) * K_DIM + chunk * 8;
    const u16* bSrc1 = W + (size_t)(nBase + 64 + rowA) * K_DIM + chunk * 8;
    char* aDst0 = (char*)As + wave * 1024;       // HW adds lane*16
    char* aDst1 = (char*)As + 4096 + wave * 1024;
    char* bDst0 = (char*)Bs + wave * 1024;
    char* bDst1 = (char*)Bs + 4096 + wave * 1024;

    // fragment read bases: lane reads [row = panel + r][chunk q^swz]. swz = (r>>1)&3 is
    // invariant under +16 (mt), +64 (waveM/N) row offsets.
    const int swzR = (r >> 1) & 3;
    const u16* aRead = As + (waveM * 64 + r) * 32 + (q ^ swzR) * 8;
    const u16* bRead = Bs + (waveN * 64 + r) * 32 + (q ^ swzR) * 8;

    for (int kt = 0; kt < K_DIM / 32; ++kt) {
        const int kOff = kt * 32;
        __builtin_amdgcn_global_load_lds((const AS1 u32*)(const void*)(aSrc0 + kOff),
                                         (AS3 u32*)(void*)aDst0, 16, 0, 0);
        __builtin_amdgcn_global_load_lds((const AS1 u32*)(const void*)(aSrc1 + kOff),
                                         (AS3 u32*)(void*)aDst1, 16, 0, 0);
        __builtin_amdgcn_global_load_lds((const AS1 u32*)(const void*)(bSrc0 + kOff),
                                         (AS3 u32*)(void*)bDst0, 16, 0, 0);
        __builtin_amdgcn_global_load_lds((const AS1 u32*)(const void*)(bSrc1 + kOff),
                                         (AS3 u32*)(void*)bDst1, 16, 0, 0);
        __syncthreads();  // compiler emits vmcnt(0) drain before s_barrier

        short8 a[4], b[4];
#pragma unroll
        for (int mt = 0; mt < 4; ++mt) a[mt] = *(const short8*)(aRead + mt * 16 * 32);
#pragma unroll
        for (int nt = 0; nt < 4; ++nt) b[nt] = *(const short8*)(bRead + nt * 16 * 32);
#pragma unroll
        for (int mt = 0; mt < 4; ++mt)
#pragma unroll
            for (int nt = 0; nt < 4; ++nt)
                acc[mt][nt] = __builtin_amdgcn_mfma_f32_16x16x32_bf16(a[mt], b[nt], acc[mt][nt], 0, 0, 0);

        __syncthreads();  // protect LDS before next stage overwrites
    }

    // epilogue: C/D layout col(n)=lane&15, row(m)=q*4+reg; fuse per-channel scale
    const int mW = mBase + waveM * 64;
    const int nW = nBase + waveN * 64;
#pragma unroll
    for (int nt = 0; nt < 4; ++nt) {
        const int n = nW + nt * 16 + r;
        const float s = scaler[n];
#pragma unroll
        for (int mt = 0; mt < 4; ++mt) {
            const int m0 = mW + mt * 16 + q * 4;
#pragma unroll
            for (int j = 0; j < 4; ++j)
                out[(size_t)(m0 + j) * N_DIM + n] = acc[mt][nt][j] * s;
        }
    }
}

// ---------------- fallback (ws too small): fp32 vector GEMM, W as int32 ----------------
__global__ void __launch_bounds__(256)
gemm_fallback_kernel(const float* __restrict__ A, const int* __restrict__ W,
                     const float* __restrict__ scaler, float* __restrict__ out) {
    __shared__ float As[64][33];
    __shared__ float Ws[64][33];
    const int tx = threadIdx.x & 15, ty = threadIdx.x >> 4;
    const int mBase = blockIdx.y * 64, nBase = blockIdx.x * 64;
    float acc[4][4] = {};
    for (int kt = 0; kt < K_DIM; kt += 32) {
        for (int i = threadIdx.x; i < 64 * 32; i += 256) {
            int rr = i >> 5, cc = i & 31;
            As[rr][cc] = A[(size_t)(mBase + rr) * K_DIM + kt + cc];
            Ws[rr][cc] = (float)W[(size_t)(nBase + rr) * K_DIM + kt + cc];
        }
        __syncthreads();
        for (int kk = 0; kk < 32; ++kk) {
            float av[4], bv[4];
#pragma unroll
            for (int i = 0; i < 4; ++i) av[i] = As[ty * 4 + i][kk];
#pragma unroll
            for (int j = 0; j < 4; ++j) bv[j] = Ws[tx * 4 + j][kk];
#pragma unroll
            for (int i = 0; i < 4; ++i)
#pragma unroll
                for (int j = 0; j < 4; ++j) acc[i][j] += av[i] * bv[j];
        }
        __syncthreads();
    }
#pragma unroll
    for (int i = 0; i < 4; ++i)
#pragma unroll
        for (int j = 0; j < 4; ++j) {
            int m = mBase + ty * 4 + i, n = nBase + tx * 4 + j;
            out[(size_t)m * N_DIM + n] = acc[i][j] * scaler[n];
        }
}

extern "C" void kernel_launch(void* const* d_in, const int* in_sizes, int n_in,
                              void* d_out, int out_size, void* d_ws, size_t ws_size,
                              hipStream_t stream) {
    const float* A      = (const float*)d_in[0];
    const int*   W32    = (const int*)d_in[1];   // int8 values materialized as int32 (verified R1/R2)
    const float* scaler = (const float*)d_in[2];
    float* out          = (float*)d_out;

    const size_t needA = (size_t)M_DIM * K_DIM * sizeof(u16);  // 64 MiB
    const size_t needW = (size_t)N_DIM * K_DIM * sizeof(u16);  // 32 MiB

    if (ws_size >= needA + needW) {
        u16* Abf = (u16*)d_ws;
        u16* Wbf = (u16*)((char*)d_ws + needA);
        cvt_a_kernel<<<4096, 256, 0, stream>>>((const float4*)A, (ushort4*)Abf, M_DIM * K_DIM / 4);
        cvt_w_kernel<<<2048, 256, 0, stream>>>((const int4*)W32, (ushort4*)Wbf, N_DIM * K_DIM / 4);
        dim3 grid(N_DIM / 128, M_DIM / 128);  // x = N tiles so consecutive blocks share the A slice
        gemm_bf16_kernel<<<grid, 256, 0, stream>>>(Abf, Wbf, scaler, out);
    } else {
        dim3 grid(N_DIM / 64, M_DIM / 64);
        gemm_fallback_kernel<<<grid, 256, 0, stream>>>(A, W32, scaler, out);
    }
}